// Round 2
// baseline (8296.980 us; speedup 1.0000x reference)
//
#include <hip/hip_runtime.h>
#include <cstdint>
#include <cstddef>

// Problem constants
#define B_    4
#define S_    2048
#define HID_  2048
#define NH_   16
#define NKV_  4
#define D_    128
#define EPS_  1e-6f
#define SCALE_ 0.08838834764831845f   // 1/sqrt(128)

// ---------------------------------------------------------------------------
// Generic fp32 GEMM: C[M,N] = A[M,K] @ W[K,N], 64x64 tile, 256 threads,
// 4x4 micro-tile per thread. MODE selects the epilogue scatter:
//   MODE 0: Wq output  -> q_buf [b][h][s][d] (idx<128) / gate [b][s][h*128+idx-128]
//   MODE 1: Wk/Wv      -> [b][hkv][s][d]
//   MODE 2: plain row-major C[m][n]
// M=8192, K=2048 (mult of 16), N in {4096,512,2048} (mult of 64): no bounds checks.
// ---------------------------------------------------------------------------
template<int MODE>
__global__ __launch_bounds__(256)
void gemm_f32(const float* __restrict__ A, const float* __restrict__ W,
              float* __restrict__ out_a, float* __restrict__ out_b,
              int M, int N, int K) {
  __shared__ float As[64][17];   // +1 pad breaks pow2 stride
  __shared__ float Bs[16][64];
  const int t  = threadIdx.x;
  const int tx = t & 15, ty = t >> 4;
  const int m0 = blockIdx.y * 64, n0 = blockIdx.x * 64;
  const int ar = t >> 2,  ac = (t & 3) * 4;    // A tile loader: 64 rows x 16 k
  const int br = t >> 4,  bc = (t & 15) * 4;   // B tile loader: 16 k x 64 cols
  float acc[4][4] = {};

  for (int k0 = 0; k0 < K; k0 += 16) {
    float4 av = *reinterpret_cast<const float4*>(&A[(size_t)(m0 + ar) * K + k0 + ac]);
    As[ar][ac + 0] = av.x; As[ar][ac + 1] = av.y;
    As[ar][ac + 2] = av.z; As[ar][ac + 3] = av.w;
    *reinterpret_cast<float4*>(&Bs[br][bc]) =
        *reinterpret_cast<const float4*>(&W[(size_t)(k0 + br) * N + n0 + bc]);
    __syncthreads();
#pragma unroll
    for (int k = 0; k < 16; ++k) {
      const float a0 = As[ty * 4 + 0][k];
      const float a1 = As[ty * 4 + 1][k];
      const float a2 = As[ty * 4 + 2][k];
      const float a3 = As[ty * 4 + 3][k];
      const float4 bv = *reinterpret_cast<float4*>(&Bs[k][tx * 4]);
      acc[0][0] += a0 * bv.x; acc[0][1] += a0 * bv.y; acc[0][2] += a0 * bv.z; acc[0][3] += a0 * bv.w;
      acc[1][0] += a1 * bv.x; acc[1][1] += a1 * bv.y; acc[1][2] += a1 * bv.z; acc[1][3] += a1 * bv.w;
      acc[2][0] += a2 * bv.x; acc[2][1] += a2 * bv.y; acc[2][2] += a2 * bv.z; acc[2][3] += a2 * bv.w;
      acc[3][0] += a3 * bv.x; acc[3][1] += a3 * bv.y; acc[3][2] += a3 * bv.z; acc[3][3] += a3 * bv.w;
    }
    __syncthreads();
  }

#pragma unroll
  for (int i = 0; i < 4; ++i) {
    const int m = m0 + ty * 4 + i;
    const int b = m >> 11;            // m / S_
    const int s = m & (S_ - 1);
#pragma unroll
    for (int j = 0; j < 4; ++j) {
      const int n = n0 + tx * 4 + j;
      const float v = acc[i][j];
      if (MODE == 0) {
        const int h = n >> 8, idx = n & 255;
        if (idx < 128)
          out_a[(((size_t)b * NH_ + h) * S_ + s) * D_ + idx] = v;
        else
          out_b[((size_t)b * S_ + s) * (size_t)HID_ + h * 128 + (idx - 128)] = v;
      } else if (MODE == 1) {
        const int h = n >> 7, d = n & 127;
        out_a[(((size_t)b * NKV_ + h) * S_ + s) * D_ + d] = v;
      } else {
        out_a[(size_t)m * N + n] = v;
      }
    }
  }
}

// ---------------------------------------------------------------------------
// Fused zero-centered RMSNorm + RoPE, in place on [b][h][s][128] rows.
// One wave (64 lanes) per row; lane l owns elements (l, l+64) — exactly the
// rotate-half pairing, so RoPE needs no cross-lane traffic.
// ---------------------------------------------------------------------------
__global__ __launch_bounds__(256)
void normrope(float* __restrict__ x, const float* __restrict__ ctab,
              const float* __restrict__ stab, const float* __restrict__ w, int H) {
  const int lane = threadIdx.x & 63;
  const long row = (long)blockIdx.x * 4 + (threadIdx.x >> 6);  // over B*H*S
  const int s = (int)(row & (S_ - 1));
  const int b = (int)(row / ((long)H * S_));
  float* xp = x + row * D_;
  const float xa = xp[lane], xb = xp[lane + 64];
  float ss = xa * xa + xb * xb;
#pragma unroll
  for (int o = 32; o; o >>= 1) ss += __shfl_xor(ss, o);
  const float r = 1.0f / sqrtf(ss * (1.0f / 128.0f) + EPS_);
  const float na = xa * r * (1.0f + w[lane]);
  const float nb = xb * r * (1.0f + w[lane + 64]);
  const float* cp = ctab + ((size_t)b * S_ + s) * D_;
  const float* sp = stab + ((size_t)b * S_ + s) * D_;
  xp[lane]      = na * cp[lane]      - nb * sp[lane];       // x1*c - x2*s
  xp[lane + 64] = nb * cp[lane + 64] + na * sp[lane + 64];  // x2*c + x1*s
}

// ---------------------------------------------------------------------------
// Raw causal scores: 32 q-rows x 64 k-cols per block. Writes score*scale only
// for j<=i (softmax never reads j>i). Fully-masked tiles exit immediately.
// LDS tiles stored K-major (transposed) so the inner loop is conflict-clean.
// ---------------------------------------------------------------------------
__global__ __launch_bounds__(256)
void scores_k(const float* __restrict__ q, const float* __restrict__ k,
              float* __restrict__ wts) {
  const int kt = blockIdx.x, qt = blockIdx.y, bz = blockIdx.z;
  const int i0 = qt * 32, j0 = kt * 64;
  if (j0 > i0 + 31) return;                       // strictly above diagonal
  const int b = bz >> 4, h = bz & 15, hk = h >> 2;  // GQA: kv head = h/4
  const float* qp = q + (((size_t)b * NH_ + h) * S_ + i0) * D_;
  const float* kp = k + (((size_t)b * NKV_ + hk) * S_ + j0) * D_;
  __shared__ float Qs[128][34];   // [kk][row]
  __shared__ float Ks[128][68];   // [kk][col], row stride 16B-aligned
  const int t = threadIdx.x;
  for (int idx = t; idx < 32 * 32; idx += 256) {
    const int row = idx >> 5, c4 = (idx & 31) * 4;
    const float4 v = *reinterpret_cast<const float4*>(&qp[row * D_ + c4]);
    Qs[c4 + 0][row] = v.x; Qs[c4 + 1][row] = v.y;
    Qs[c4 + 2][row] = v.z; Qs[c4 + 3][row] = v.w;
  }
  for (int idx = t; idx < 64 * 32; idx += 256) {
    const int row = idx >> 5, c4 = (idx & 31) * 4;
    const float4 v = *reinterpret_cast<const float4*>(&kp[row * D_ + c4]);
    Ks[c4 + 0][row] = v.x; Ks[c4 + 1][row] = v.y;
    Ks[c4 + 2][row] = v.z; Ks[c4 + 3][row] = v.w;
  }
  __syncthreads();
  const int tx = t & 15, ty = t >> 4;
  float acc[2][4] = {};
#pragma unroll 4
  for (int kk = 0; kk < 128; ++kk) {
    const float a0 = Qs[kk][ty * 2 + 0];
    const float a1 = Qs[kk][ty * 2 + 1];
    const float4 bv = *reinterpret_cast<float4*>(&Ks[kk][tx * 4]);
    acc[0][0] += a0 * bv.x; acc[0][1] += a0 * bv.y; acc[0][2] += a0 * bv.z; acc[0][3] += a0 * bv.w;
    acc[1][0] += a1 * bv.x; acc[1][1] += a1 * bv.y; acc[1][2] += a1 * bv.z; acc[1][3] += a1 * bv.w;
  }
#pragma unroll
  for (int r = 0; r < 2; ++r) {
    const int i = i0 + ty * 2 + r;
    const size_t rowbase = ((size_t)bz * S_ + i) * (size_t)S_;
#pragma unroll
    for (int c = 0; c < 4; ++c) {
      const int j = j0 + tx * 4 + c;
      if (j <= i) wts[rowbase + j] = acc[r][c] * SCALE_;
    }
  }
}

// ---------------------------------------------------------------------------
// Row softmax in place. Reads j<=i (raw scores), writes the whole row
// (exact zeros for j>i, matching the reference's exp(-1e9-max) underflow).
// ---------------------------------------------------------------------------
__global__ __launch_bounds__(256)
void softmax_k(float* __restrict__ wts) {
  const int i = blockIdx.x;
  float* row = wts + ((size_t)blockIdx.y * S_ + i) * (size_t)S_;
  const int t = threadIdx.x;
  const int n = i + 1;
  float x[8], e[8];
  float mx = -3.0e38f;
#pragma unroll
  for (int u = 0; u < 8; ++u) {
    const int j = t + u * 256;
    x[u] = (j < n) ? row[j] : -3.0e38f;
    mx = fmaxf(mx, x[u]);
  }
  __shared__ float red[4];
#pragma unroll
  for (int o = 32; o; o >>= 1) mx = fmaxf(mx, __shfl_xor(mx, o));
  if ((t & 63) == 0) red[t >> 6] = mx;
  __syncthreads();
  mx = fmaxf(fmaxf(red[0], red[1]), fmaxf(red[2], red[3]));
  __syncthreads();
  float sum = 0.f;
#pragma unroll
  for (int u = 0; u < 8; ++u) {
    const int j = t + u * 256;
    e[u] = (j < n) ? expf(x[u] - mx) : 0.f;
    sum += e[u];
  }
#pragma unroll
  for (int o = 32; o; o >>= 1) sum += __shfl_xor(sum, o);
  if ((t & 63) == 0) red[t >> 6] = sum;
  __syncthreads();
  const float inv = 1.0f / (red[0] + red[1] + red[2] + red[3]);
#pragma unroll
  for (int u = 0; u < 8; ++u) row[t + u * 256] = e[u] * inv;
}

// ---------------------------------------------------------------------------
// PV: out[b,h,i,:] = sum_j w[i,j] * v[j,:], causal tiles only (weights beyond
// the diagonal are exact zeros, so no masking). Fused epilogue applies
// sigmoid(gate) and scatters to [b][s][h*128+d] for the Wo GEMM.
// 32 q-rows per block, full D=128, K-tile 64.
// ---------------------------------------------------------------------------
__global__ __launch_bounds__(256)
void pv_k(const float* __restrict__ wts, const float* __restrict__ v,
          const float* __restrict__ gate, float* __restrict__ ao) {
  const int qt = blockIdx.x, bz = blockIdx.y;
  const int b = bz >> 4, h = bz & 15, hk = h >> 2;
  const int i0 = qt * 32;
  const float* vp = v + ((size_t)b * NKV_ + hk) * S_ * D_;
  const float* wp = wts + ((size_t)bz * S_ + i0) * (size_t)S_;
  __shared__ float Ws[32][65];
  __shared__ float Vs[64][128];
  const int t = threadIdx.x;
  const int r = t >> 3, c8 = (t & 7) * 4;   // row 0..31, col base
  float4 acc[4];
#pragma unroll
  for (int qd = 0; qd < 4; ++qd) acc[qd] = make_float4(0.f, 0.f, 0.f, 0.f);

  const int ktmax = (i0 + 31) >> 6;
  for (int kt = 0; kt <= ktmax; ++kt) {
    const int j0 = kt * 64;
    for (int idx = t; idx < 512; idx += 256) {
      const int rr = idx >> 4, cc = (idx & 15) * 4;
      const float4 w4 = *reinterpret_cast<const float4*>(&wp[(size_t)rr * S_ + j0 + cc]);
      Ws[rr][cc + 0] = w4.x; Ws[rr][cc + 1] = w4.y;
      Ws[rr][cc + 2] = w4.z; Ws[rr][cc + 3] = w4.w;
    }
    for (int idx = t; idx < 2048; idx += 256) {
      const int rr = idx >> 5, cc = (idx & 31) * 4;
      *reinterpret_cast<float4*>(&Vs[rr][cc]) =
          *reinterpret_cast<const float4*>(&vp[(size_t)(j0 + rr) * D_ + cc]);
    }
    __syncthreads();
#pragma unroll 8
    for (int j = 0; j < 64; ++j) {
      const float w = Ws[r][j];
      const float4 v0 = *reinterpret_cast<float4*>(&Vs[j][c8]);
      const float4 v1 = *reinterpret_cast<float4*>(&Vs[j][c8 + 32]);
      const float4 v2 = *reinterpret_cast<float4*>(&Vs[j][c8 + 64]);
      const float4 v3 = *reinterpret_cast<float4*>(&Vs[j][c8 + 96]);
      acc[0].x += w * v0.x; acc[0].y += w * v0.y; acc[0].z += w * v0.z; acc[0].w += w * v0.w;
      acc[1].x += w * v1.x; acc[1].y += w * v1.y; acc[1].z += w * v1.z; acc[1].w += w * v1.w;
      acc[2].x += w * v2.x; acc[2].y += w * v2.y; acc[2].z += w * v2.z; acc[2].w += w * v2.w;
      acc[3].x += w * v3.x; acc[3].y += w * v3.y; acc[3].z += w * v3.z; acc[3].w += w * v3.w;
    }
    __syncthreads();
  }

  const int i = i0 + r;
  const size_t obase = ((size_t)b * S_ + i) * (size_t)HID_ + h * D_;
#pragma unroll
  for (int qd = 0; qd < 4; ++qd) {
    const int d = c8 + qd * 32;
    const float4 g = *reinterpret_cast<const float4*>(&gate[obase + d]);
    float4 o;
    o.x = acc[qd].x / (1.f + expf(-g.x));
    o.y = acc[qd].y / (1.f + expf(-g.y));
    o.z = acc[qd].z / (1.f + expf(-g.z));
    o.w = acc[qd].w / (1.f + expf(-g.w));
    *reinterpret_cast<float4*>(&ao[obase + d]) = o;
  }
}

// ---------------------------------------------------------------------------
// Workspace layout (160 MB concurrent; ao aliases q_buf — q is dead after
// scores_k, and all launches are stream-ordered):
//   q_buf/ao : B*NH*S*D  = 16.8M f (64 MB)
//   k_buf    : B*NKV*S*D =  4.2M f (16 MB)
//   v_buf    : B*NKV*S*D =  4.2M f (16 MB)
//   gate     : B*S*HID   = 16.8M f (64 MB)
// ---------------------------------------------------------------------------
extern "C" void kernel_launch(void* const* d_in, const int* in_sizes, int n_in,
                              void* d_out, int out_size, void* d_ws, size_t ws_size,
                              hipStream_t stream) {
  const float* hs   = (const float*)d_in[0];
  const float* ctab = (const float*)d_in[1];
  const float* stab = (const float*)d_in[2];
  // d_in[3] = attention_mask: pure causal, applied analytically
  const float* Wq = (const float*)d_in[4];
  const float* Wk = (const float*)d_in[5];
  const float* Wv = (const float*)d_in[6];
  const float* Wo = (const float*)d_in[7];
  const float* qw = (const float*)d_in[8];
  const float* kw = (const float*)d_in[9];

  float* out = (float*)d_out;                       // attn_output: B*S*HID
  float* wts = out + (size_t)B_ * S_ * HID_;        // attn_weights: B*NH*S*S

  float* ws    = (float*)d_ws;
  float* q_buf = ws;                                 // [B][NH][S][D]
  float* k_buf = q_buf + (size_t)B_ * NH_ * S_ * D_; // [B][NKV][S][D]
  float* v_buf = k_buf + (size_t)B_ * NKV_ * S_ * D_;
  float* gate  = v_buf + (size_t)B_ * NKV_ * S_ * D_; // [B][S][HID]
  float* ao    = q_buf;                               // alias: q dead after scores

  const int M = B_ * S_;
  const dim3 blk(256);

  gemm_f32<0><<<dim3((NH_ * D_ * 2) / 64, M / 64), blk, 0, stream>>>(hs, Wq, q_buf, gate, M, NH_ * D_ * 2, HID_);
  gemm_f32<1><<<dim3((NKV_ * D_) / 64, M / 64), blk, 0, stream>>>(hs, Wk, k_buf, nullptr, M, NKV_ * D_, HID_);
  gemm_f32<1><<<dim3((NKV_ * D_) / 64, M / 64), blk, 0, stream>>>(hs, Wv, v_buf, nullptr, M, NKV_ * D_, HID_);
  normrope<<<dim3(B_ * NH_ * S_ / 4), blk, 0, stream>>>(q_buf, ctab, stab, qw, NH_);
  normrope<<<dim3(B_ * NKV_ * S_ / 4), blk, 0, stream>>>(k_buf, ctab, stab, kw, NKV_);
  scores_k<<<dim3(S_ / 64, S_ / 32, B_ * NH_), blk, 0, stream>>>(q_buf, k_buf, wts);
  softmax_k<<<dim3(S_, B_ * NH_), blk, 0, stream>>>(wts);
  pv_k<<<dim3(S_ / 32, B_ * NH_), blk, 0, stream>>>(wts, v_buf, gate, ao);
  gemm_f32<2><<<dim3(HID_ / 64, M / 64), blk, 0, stream>>>(ao, Wo, out, nullptr, M, HID_, HID_);
}